// Round 6
// baseline (378.950 us; speedup 1.0000x reference)
//
#include <hip/hip_runtime.h>
#include <hip/hip_bf16.h>
#include <cstdint>
#include <cstddef>

typedef __bf16 bf16_t;
typedef __attribute__((ext_vector_type(8))) __bf16 bf16x8;
typedef __attribute__((ext_vector_type(4))) __bf16 bf16x4;
typedef __attribute__((ext_vector_type(4))) float f32x4;

#define B_ 2
#define T_ 2048
#define DIM_ 2048
#define H_ 16
#define DH_ 128
#define DD_ 64
#define DQK_ 192              // DH_ + DD_
#define QSTRIDE_ 3072         // H_ * DQK_
#define BT_ 4096              // B_ * T_

__device__ __forceinline__ void gload16(const void* g, void* lds) {
  __builtin_amdgcn_global_load_lds(
      (const __attribute__((address_space(1))) unsigned int*)g,
      (__attribute__((address_space(3))) unsigned int*)lds, 16, 0, 0);
}

// ---------------- cast x (fp32 -> bf16, vectorized) ----------------
struct bf16_4 { bf16_t a, b, c, d; };
__global__ void cast_f32_bf16(const float* __restrict__ in, bf16_t* __restrict__ out, int n4) {
  int i = blockIdx.x * blockDim.x + threadIdx.x;
  if (i >= n4) return;
  float4 v = ((const float4*)in)[i];
  bf16_4 r{(bf16_t)v.x, (bf16_t)v.y, (bf16_t)v.z, (bf16_t)v.w};
  ((bf16_4*)out)[i] = r;
}

// ------------- transpose + cast weight: W (K x N) fp32 -> Wt (Np x K) bf16 -------------
__global__ void transpose_cast(const float* __restrict__ W, bf16_t* __restrict__ Wt,
                               int K, int N, int Np) {
  __shared__ float tile[32][33];
  int k0 = blockIdx.x * 32, n0 = blockIdx.y * 32;
  int tx = threadIdx.x, ty = threadIdx.y;
#pragma unroll
  for (int i = 0; i < 4; ++i) {
    int k = k0 + ty + i * 8, n = n0 + tx;
    float v = (k < K && n < N) ? W[(size_t)k * N + n] : 0.f;
    tile[ty + i * 8][tx] = v;
  }
  __syncthreads();
#pragma unroll
  for (int i = 0; i < 4; ++i) {
    int n = n0 + ty + i * 8, k = k0 + tx;
    if (n < Np && k < K) Wt[(size_t)n * K + k] = (bf16_t)tile[tx][ty + i * 8];
  }
}

// ------------- transpose V: Vbuf[BT][2048] -> Vt[bh=32][128][T] -------------
__global__ void transpose_v(const bf16_t* __restrict__ V, bf16_t* __restrict__ Vt) {
  __shared__ bf16_t tile[64 * 64];
  int id = blockIdx.x;
  int t0 = (id & 31) * 64;
  int d0 = ((id >> 5) & 1) * 64;
  int bh = id >> 6;  // 0..31
  int b = bh >> 4, h = bh & 15;
  int t = threadIdx.x;
#pragma unroll
  for (int it = 0; it < 2; ++it) {
    int idx = it * 256 + t;
    int tt = idx >> 3, c = idx & 7;
    bf16x8 v = *(const bf16x8*)&V[(size_t)(b * T_ + t0 + tt) * 2048 + h * 128 + d0 + c * 8];
    int sw = (tt ^ (tt >> 3)) & 7;
    *(bf16x8*)((char*)tile + tt * 128 + 16 * (c ^ sw)) = v;
  }
  __syncthreads();
#pragma unroll
  for (int it = 0; it < 2; ++it) {
    int idx = it * 256 + t;
    int dr = idx >> 3, c = idx & 7;
    bf16_t tmp[8];
#pragma unroll
    for (int u = 0; u < 8; ++u) {
      int sw = (u ^ c) & 7;
      tmp[u] = *(const bf16_t*)((const char*)tile + (8 * c + u) * 128 + ((2 * dr) ^ (16 * sw)));
    }
    *(bf16x8*)&Vt[((size_t)bh * 128 + d0 + dr) * T_ + t0 + c * 8] = *(bf16x8*)tmp;
  }
}

// ---------------- GEMM: C = A(MxK) * Bt(NxK)^T, bf16 in, fp32 acc ----------------
// MODE 1: store fp32 to C0, row stride ldc
// MODE 3: col<512 -> C0 (q_c); col<1024 -> C1 (kv_c); col<1088 -> C2 (k_rb); else skip
// MODE 4: col<2048 -> C0 head-interleaved (Qbuf); else -> C1 ld 1024 (q_rb)
// MODE 5: col<2048 -> C0 head-interleaved (Kbuf); else -> C1 ld 2048 (Vbuf)
template <int MODE>
__global__ __launch_bounds__(256) void gemm_bt(const bf16_t* __restrict__ A,
                                               const bf16_t* __restrict__ Bt,
                                               void* __restrict__ C0v,
                                               void* __restrict__ C1v,
                                               void* __restrict__ C2v,
                                               int M, int N, int K, int ldc) {
  __shared__ bf16_t As[128 * 32];
  __shared__ bf16_t Bs[128 * 32];
  const int t = threadIdx.x;
  const int w = t >> 6, l = t & 63, l15 = l & 15, lhi = l >> 4;
  const int m0 = blockIdx.y * 128, n0 = blockIdx.x * 128;
  const int wr = (w >> 1) * 64, wc = (w & 1) * 64;

  f32x4 zero = {0.f, 0.f, 0.f, 0.f};
  f32x4 acc[4][4];
#pragma unroll
  for (int m = 0; m < 4; ++m)
#pragma unroll
    for (int n = 0; n < 4; ++n) acc[m][n] = zero;

  const int e0 = t * 8;
  const int r0 = e0 >> 5, c0 = e0 & 31;
  const int e1 = 2048 + t * 8;
  const int r1 = e1 >> 5, c1 = e1 & 31;

  for (int k0 = 0; k0 < K; k0 += 32) {
    gload16(A + (size_t)(m0 + r0) * K + k0 + c0, &As[e0]);
    gload16(A + (size_t)(m0 + r1) * K + k0 + c1, &As[e1]);
    gload16(Bt + (size_t)(n0 + r0) * K + k0 + c0, &Bs[e0]);
    gload16(Bt + (size_t)(n0 + r1) * K + k0 + c1, &Bs[e1]);
    __syncthreads();
    bf16x8 af[4], bfr[4];
#pragma unroll
    for (int m = 0; m < 4; ++m)
      af[m] = *(const bf16x8*)&As[(wr + m * 16 + l15) * 32 + lhi * 8];
#pragma unroll
    for (int n = 0; n < 4; ++n)
      bfr[n] = *(const bf16x8*)&Bs[(wc + n * 16 + l15) * 32 + lhi * 8];
#pragma unroll
    for (int m = 0; m < 4; ++m)
#pragma unroll
      for (int n = 0; n < 4; ++n)
        acc[m][n] = __builtin_amdgcn_mfma_f32_16x16x32_bf16(af[m], bfr[n], acc[m][n], 0, 0, 0);
    __syncthreads();
  }

#pragma unroll
  for (int m = 0; m < 4; ++m) {
#pragma unroll
    for (int n = 0; n < 4; ++n) {
#pragma unroll
      for (int r = 0; r < 4; ++r) {
        int row = m0 + wr + m * 16 + lhi * 4 + r;
        int col = n0 + wc + n * 16 + l15;
        float v = acc[m][n][r];
        if (MODE == 1) {
          ((float*)C0v)[(size_t)row * ldc + col] = v;
        } else if (MODE == 3) {
          if (col < 512)       ((bf16_t*)C0v)[(size_t)row * 512 + col] = (bf16_t)v;
          else if (col < 1024) ((bf16_t*)C1v)[(size_t)row * 512 + (col - 512)] = (bf16_t)v;
          else if (col < 1088) ((bf16_t*)C2v)[(size_t)row * 64 + (col - 1024)] = (bf16_t)v;
        } else if (MODE == 4) {
          if (col < 2048) ((bf16_t*)C0v)[(size_t)row * QSTRIDE_ + (col >> 7) * DQK_ + (col & 127)] = (bf16_t)v;
          else            ((bf16_t*)C1v)[(size_t)row * 1024 + (col - 2048)] = (bf16_t)v;
        } else if (MODE == 5) {
          if (col < 2048) ((bf16_t*)C0v)[(size_t)row * QSTRIDE_ + (col >> 7) * DQK_ + (col & 127)] = (bf16_t)v;
          else            ((bf16_t*)C1v)[(size_t)row * 2048 + (col - 2048)] = (bf16_t)v;
        }
      }
    }
  }
}

// ---------------- RoPE epilogues ----------------
__global__ void rope_q(const bf16_t* __restrict__ qr, const float* __restrict__ fr,
                       bf16_t* __restrict__ Q) {
  int idx = blockIdx.x * 256 + threadIdx.x;  // BT_*H_*32
  int j = idx & 31;
  int h = (idx >> 5) & 15;
  int row = idx >> 9;
  int tt = row & (T_ - 1);
  float x1 = (float)qr[(size_t)row * 1024 + h * 64 + 2 * j];
  float x2 = (float)qr[(size_t)row * 1024 + h * 64 + 2 * j + 1];
  float c = fr[tt * 64 + 2 * j], s = fr[tt * 64 + 2 * j + 1];
  bf16_t o0 = (bf16_t)(x1 * c - x2 * s);
  bf16_t o1 = (bf16_t)(x1 * s + x2 * c);
  size_t o = (size_t)row * QSTRIDE_ + h * DQK_ + 128 + 2 * j;
  Q[o] = o0;
  Q[o + 1] = o1;
}

__global__ void rope_k(const bf16_t* __restrict__ kr, const float* __restrict__ fr,
                       bf16_t* __restrict__ Kb) {
  int idx = blockIdx.x * 256 + threadIdx.x;  // BT_*32
  int j = idx & 31;
  int row = idx >> 5;
  int tt = row & (T_ - 1);
  float x1 = (float)kr[(size_t)row * 64 + 2 * j];
  float x2 = (float)kr[(size_t)row * 64 + 2 * j + 1];
  float c = fr[tt * 64 + 2 * j], s = fr[tt * 64 + 2 * j + 1];
  union { bf16_t h2[2]; unsigned u; } pk;
  pk.h2[0] = (bf16_t)(x1 * c - x2 * s);
  pk.h2[1] = (bf16_t)(x1 * s + x2 * c);
#pragma unroll
  for (int h = 0; h < H_; ++h) {
    *(unsigned*)&Kb[(size_t)row * QSTRIDE_ + h * DQK_ + 128 + 2 * j] = pk.u;
  }
}

// ---------------- causal flash attention v4 ----------------
// 256 blocks x 256 threads, 1 block/CU. Block = (bh, q-tile pair {qp, 15-qp}),
// q-tiles of 128 rows, 4 waves x 32 rows (2 fragment sets/wave -> LDS reads halved).
// K/V staged via global_load_lds into LINEAR LDS with pre-swizzled global source
// (XOR row&7 on 16B-slot index); reads apply the same XOR -> 2-way (free).
// Double-buffered: one barrier per k-step. 99328 B dynamic LDS.
#define KSLOT 24
#define KBYTES (64 * KSLOT * 16)      // 24576
#define VSLOT 8
#define VBYTES (128 * VSLOT * 16)     // 16384
#define PLDB 68
#define PSBYTES (4 * 32 * PLDB * 2)   // 17408
#define SMEM_TOTAL (2 * KBYTES + 2 * VBYTES + PSBYTES)  // 99328

__global__ __launch_bounds__(256, 1) void flash_attn4(const bf16_t* __restrict__ Q,
                                                      const bf16_t* __restrict__ Kb,
                                                      const bf16_t* __restrict__ Vt,
                                                      bf16_t* __restrict__ Ob) {
  extern __shared__ char smem[];
  char* ksmem = smem;                          // [2][KBYTES]
  char* vsmem = smem + 2 * KBYTES;             // [2][VBYTES]
  bf16_t* Ps = (bf16_t*)(smem + 2 * KBYTES + 2 * VBYTES);

  const int t = threadIdx.x, w = t >> 6, l = t & 63, l15 = l & 15, lhi = l >> 4;
  const int id = blockIdx.x;
  const int bh = id & 31, qp = id >> 5;        // same-bh blocks share XCD (id%8 pattern)
  const int b = bh >> 4, h = bh & 15;
  const int qa = qp, qb = 15 - qp;
  const float scale = 0.07216878364870322f;    // 1/sqrt(192)

  const bf16_t* kbase = Kb + (size_t)b * T_ * QSTRIDE_ + h * DQK_;
  const bf16_t* vbase = Vt + (size_t)bh * DH_ * T_;

  // staging source offsets (pre-swizzled): linear LDS slot i holds global slot s = p ^ (r&7)
  int koff[6];
#pragma unroll
  for (int j = 0; j < 6; ++j) {
    int i = j * 256 + t;
    int r = i / 24, p = i % 24;
    int s = (p & ~7) | ((p & 7) ^ (r & 7));
    koff[j] = r * QSTRIDE_ + s * 8;
  }
  int voff[4];
#pragma unroll
  for (int j = 0; j < 4; ++j) {
    int i = j * 256 + t;
    int r = i >> 3, p = i & 7;
    int s = p ^ (r & 7);
    voff[j] = r * T_ + s * 8;
  }
  const int xk = l15 & 7;  // read-side XOR

  auto STAGE = [&](int buf, int k0) {
    const bf16_t* kg = kbase + (size_t)k0 * QSTRIDE_;
    char* kd = ksmem + buf * KBYTES + w * 1024;
#pragma unroll
    for (int j = 0; j < 6; ++j) gload16(kg + koff[j], kd + j * 4096);
    const bf16_t* vg = vbase + k0;
    char* vd = vsmem + buf * VBYTES + w * 1024;
#pragma unroll
    for (int j = 0; j < 4; ++j) gload16(vg + voff[j], vd + j * 4096);
  };

  f32x4 zero = {0.f, 0.f, 0.f, 0.f};
  int cur = 0;
  STAGE(0, 0);

  for (int pass = 0; pass < 2; ++pass) {
    const int q = pass ? qb : qa;
    const int nkt = 2 * q + 2;
    const int myLast = 2 * q + (w >= 2 ? 1 : 0);  // waves 0,1 skip the final (fully-masked) k-tile

    bf16x8 qf[2][6];
#pragma unroll
    for (int u = 0; u < 2; ++u) {
      const bf16_t* qrow = Q + ((size_t)(b * T_ + q * 128 + w * 32 + u * 16 + l15)) * QSTRIDE_ + h * DQK_;
#pragma unroll
      for (int kc = 0; kc < 6; ++kc) qf[u][kc] = *(const bf16x8*)(qrow + kc * 32 + lhi * 8);
    }

    float m_r[2][4], l_r[2][4];
    f32x4 accO[2][8];
#pragma unroll
    for (int u = 0; u < 2; ++u) {
#pragma unroll
      for (int r = 0; r < 4; ++r) { m_r[u][r] = -1e30f; l_r[u][r] = 0.f; }
#pragma unroll
      for (int n = 0; n < 8; ++n) accO[u][n] = zero;
    }

    for (int kt = 0; kt < nkt; ++kt) {
      const bool lastStep = (pass == 1) && (kt == nkt - 1);
      if (!lastStep) STAGE(cur ^ 1, (kt == nkt - 1) ? 0 : (kt + 1) * 64);

      if (kt <= myLast) {
        const char* ks = ksmem + cur * KBYTES;
        const char* vs = vsmem + cur * VBYTES;
        const bool diag = (kt == myLast);

        f32x4 s[2][4];
#pragma unroll
        for (int u = 0; u < 2; ++u)
#pragma unroll
          for (int n = 0; n < 4; ++n) s[u][n] = zero;
#pragma unroll
        for (int kc = 0; kc < 6; ++kc) {
          const int sl = 4 * kc + lhi;
          const int p = (sl & ~7) | ((sl & 7) ^ xk);
#pragma unroll
          for (int n = 0; n < 4; ++n) {
            bf16x8 kf = *(const bf16x8*)(ks + ((n * 16 + l15) * KSLOT + p) * 16);
            s[0][n] = __builtin_amdgcn_mfma_f32_16x16x32_bf16(qf[0][kc], kf, s[0][n], 0, 0, 0);
            s[1][n] = __builtin_amdgcn_mfma_f32_16x16x32_bf16(qf[1][kc], kf, s[1][n], 0, 0, 0);
          }
        }

#pragma unroll
        for (int u = 0; u < 2; ++u) {
#pragma unroll
          for (int n = 0; n < 4; ++n)
#pragma unroll
            for (int r = 0; r < 4; ++r) {
              float v = s[u][n][r] * scale;
              if (diag) {
                int qq = (w & 1) * 32 + u * 16 + lhi * 4 + r;
                int kk = n * 16 + l15;
                if (kk > qq) v = -1e30f;
              }
              s[u][n][r] = v;
            }
          float mn[4], corr[4];
#pragma unroll
          for (int r = 0; r < 4; ++r) {
            float v = fmaxf(fmaxf(s[u][0][r], s[u][1][r]), fmaxf(s[u][2][r], s[u][3][r]));
#pragma unroll
            for (int off = 1; off < 16; off <<= 1) v = fmaxf(v, __shfl_xor(v, off, 64));
            mn[r] = fmaxf(m_r[u][r], v);
            corr[r] = __expf(m_r[u][r] - mn[r]);
            m_r[u][r] = mn[r];
          }
          float rs[4] = {0.f, 0.f, 0.f, 0.f};
#pragma unroll
          for (int n = 0; n < 4; ++n)
#pragma unroll
            for (int r = 0; r < 4; ++r) {
              float p = __expf(s[u][n][r] - mn[r]);
              rs[r] += p;
              Ps[(w * 32 + u * 16 + lhi * 4 + r) * PLDB + n * 16 + l15] = (bf16_t)p;
            }
#pragma unroll
          for (int r = 0; r < 4; ++r) {
            float v = rs[r];
#pragma unroll
            for (int off = 1; off < 16; off <<= 1) v += __shfl_xor(v, off, 64);
            l_r[u][r] = l_r[u][r] * corr[r] + v;
          }
#pragma unroll
          for (int n = 0; n < 8; ++n)
#pragma unroll
            for (int r = 0; r < 4; ++r) accO[u][n][r] *= corr[r];
        }

        // PV: O += P(32x64) @ V(64x128), vf shared across both u
#pragma unroll
        for (int kc = 0; kc < 2; ++kc) {
          bf16x8 pfu[2];
#pragma unroll
          for (int u = 0; u < 2; ++u) {
            const bf16_t* pb = Ps + (w * 32 + u * 16 + l15) * PLDB + kc * 32 + lhi * 8;
            bf16x4 p0 = *(const bf16x4*)pb;
            bf16x4 p1 = *(const bf16x4*)(pb + 4);
            pfu[u] = __builtin_shufflevector(p0, p1, 0, 1, 2, 3, 4, 5, 6, 7);
          }
          const int sv = 4 * kc + lhi;
          const int pv = sv ^ xk;
#pragma unroll
          for (int n = 0; n < 8; ++n) {
            bf16x8 vf = *(const bf16x8*)(vs + ((n * 16 + l15) * VSLOT + pv) * 16);
            accO[0][n] = __builtin_amdgcn_mfma_f32_16x16x32_bf16(pfu[0], vf, accO[0][n], 0, 0, 0);
            accO[1][n] = __builtin_amdgcn_mfma_f32_16x16x32_bf16(pfu[1], vf, accO[1][n], 0, 0, 0);
          }
        }
      }

      __syncthreads();  // reads of buf[cur] done AND buf[cur^1] staging complete
      cur ^= 1;
    }

    // store O for this q-tile
#pragma unroll
    for (int u = 0; u < 2; ++u) {
      float inv[4];
#pragma unroll
      for (int r = 0; r < 4; ++r) inv[r] = 1.0f / l_r[u][r];
#pragma unroll
      for (int n = 0; n < 8; ++n)
#pragma unroll
        for (int r = 0; r < 4; ++r) {
          size_t row = (size_t)(b * T_ + q * 128 + w * 32 + u * 16 + lhi * 4 + r);
          Ob[row * (H_ * DH_) + h * DH_ + n * 16 + l15] = (bf16_t)(accO[u][n][r] * inv[r]);
        }
    }
  }
}

// ---------------- host ----------------
extern "C" void kernel_launch(void* const* d_in, const int* in_sizes, int n_in,
                              void* d_out, int out_size, void* d_ws, size_t ws_size,
                              hipStream_t stream) {
  (void)in_sizes; (void)n_in; (void)out_size; (void)ws_size;
  const float* x    = (const float*)d_in[0];
  const float* fr   = (const float*)d_in[1];
  // d_in[2] = mask (unused; causal handled analytically)
  const float* Wdq  = (const float*)d_in[3];
  const float* Wuq  = (const float*)d_in[4];
  const float* Wdkv = (const float*)d_in[5];
  const float* Wuk  = (const float*)d_in[6];
  const float* Wuv  = (const float*)d_in[7];
  const float* Wqr  = (const float*)d_in[8];
  const float* Wkr  = (const float*)d_in[9];
  const float* Wo   = (const float*)d_in[10];
  float* out = (float*)d_out;

  char* ws = (char*)d_ws;
  size_t off = 0;
  auto alloc = [&](size_t bytes) -> void* {
    void* p = ws + off;
    off += (bytes + 255) & ~(size_t)255;
    return p;
  };
  bf16_t* x_bf   = (bf16_t*)alloc((size_t)BT_ * DIM_ * 2);
  bf16_t* Bt1    = (bf16_t*)alloc((size_t)1152 * 2048 * 2);  // [Wdq(512) | Wdkv(512) | Wkr(128 pad)]
  bf16_t* Bt2    = (bf16_t*)alloc((size_t)3072 * 512 * 2);   // [Wuq(2048) | Wqr(1024)]
  bf16_t* Bt3    = (bf16_t*)alloc((size_t)4096 * 512 * 2);   // [Wuk(2048) | Wuv(2048)]
  bf16_t* Wo_t   = (bf16_t*)alloc((size_t)2048 * 2048 * 2);
  bf16_t* q_c    = (bf16_t*)alloc((size_t)BT_ * 512 * 2);
  bf16_t* kv_c   = (bf16_t*)alloc((size_t)BT_ * 512 * 2);
  bf16_t* q_rb   = (bf16_t*)alloc((size_t)BT_ * 1024 * 2);
  bf16_t* k_rb   = (bf16_t*)alloc((size_t)BT_ * 64 * 2);
  bf16_t* Qbuf   = (bf16_t*)alloc((size_t)BT_ * QSTRIDE_ * 2);
  bf16_t* Kbuf   = (bf16_t*)alloc((size_t)BT_ * QSTRIDE_ * 2);
  bf16_t* Vbuf   = (bf16_t*)alloc((size_t)BT_ * 2048 * 2);
  bf16_t* Vt_g   = (bf16_t*)alloc((size_t)BT_ * 2048 * 2);
  bf16_t* AObuf  = (bf16_t*)alloc((size_t)BT_ * 2048 * 2);

  dim3 tb(32, 8);
  cast_f32_bf16<<<(BT_ * DIM_ / 4 + 255) / 256, 256, 0, stream>>>(x, x_bf, BT_ * DIM_ / 4);
  transpose_cast<<<dim3(64, 16), tb, 0, stream>>>(Wdq,  Bt1,                        2048, 512, 512);
  transpose_cast<<<dim3(64, 16), tb, 0, stream>>>(Wdkv, Bt1 + (size_t)512 * 2048,   2048, 512, 512);
  transpose_cast<<<dim3(64, 4),  tb, 0, stream>>>(Wkr,  Bt1 + (size_t)1024 * 2048,  2048, 64, 128);
  transpose_cast<<<dim3(16, 64), tb, 0, stream>>>(Wuq,  Bt2,                        512, 2048, 2048);
  transpose_cast<<<dim3(16, 32), tb, 0, stream>>>(Wqr,  Bt2 + (size_t)2048 * 512,   512, 1024, 1024);
  transpose_cast<<<dim3(16, 64), tb, 0, stream>>>(Wuk,  Bt3,                        512, 2048, 2048);
  transpose_cast<<<dim3(16, 64), tb, 0, stream>>>(Wuv,  Bt3 + (size_t)2048 * 512,   512, 2048, 2048);
  transpose_cast<<<dim3(64, 64), tb, 0, stream>>>(Wo,   Wo_t,                       2048, 2048, 2048);

  // fused projections
  gemm_bt<3><<<dim3(9, 32),  256, 0, stream>>>(x_bf, Bt1, q_c, kv_c, k_rb, BT_, 1088, 2048, 0);
  gemm_bt<4><<<dim3(24, 32), 256, 0, stream>>>(q_c,  Bt2, Qbuf, q_rb, nullptr, BT_, 3072, 512, 0);
  gemm_bt<5><<<dim3(32, 32), 256, 0, stream>>>(kv_c, Bt3, Kbuf, Vbuf, nullptr, BT_, 4096, 512, 0);

  transpose_v<<<2048, 256, 0, stream>>>(Vbuf, Vt_g);

  rope_q<<<(BT_ * H_ * 32) / 256, 256, 0, stream>>>(q_rb, fr, Qbuf);
  rope_k<<<(BT_ * 32) / 256, 256, 0, stream>>>(k_rb, fr, Kbuf);

  hipFuncSetAttribute((const void*)flash_attn4,
                      hipFuncAttributeMaxDynamicSharedMemorySize, SMEM_TOTAL);
  flash_attn4<<<256, 256, SMEM_TOTAL, stream>>>(Qbuf, Kbuf, Vt_g, AObuf);

  // output projection -> fp32
  gemm_bt<1><<<dim3(16, 32), 256, 0, stream>>>(AObuf, Wo_t, out, nullptr, nullptr, BT_, 2048, 2048, 2048);
}

// Round 7
// 347.051 us; speedup vs baseline: 1.0919x; 1.0919x over previous
//
#include <hip/hip_runtime.h>
#include <hip/hip_bf16.h>
#include <cstdint>
#include <cstddef>

typedef __bf16 bf16_t;
typedef __attribute__((ext_vector_type(8))) __bf16 bf16x8;
typedef __attribute__((ext_vector_type(4))) __bf16 bf16x4;
typedef __attribute__((ext_vector_type(4))) float f32x4;

#define B_ 2
#define T_ 2048
#define DIM_ 2048
#define H_ 16
#define DH_ 128
#define DD_ 64
#define DQK_ 192              // DH_ + DD_
#define QSTRIDE_ 3072         // H_ * DQK_
#define BT_ 4096              // B_ * T_

__device__ __forceinline__ void gload16(const void* g, void* lds) {
  __builtin_amdgcn_global_load_lds(
      (const __attribute__((address_space(1))) unsigned int*)g,
      (__attribute__((address_space(3))) unsigned int*)lds, 16, 0, 0);
}

// ---------------- cast x (fp32 -> bf16, vectorized) ----------------
struct bf16_4 { bf16_t a, b, c, d; };
__global__ void cast_f32_bf16(const float* __restrict__ in, bf16_t* __restrict__ out, int n4) {
  int i = blockIdx.x * blockDim.x + threadIdx.x;
  if (i >= n4) return;
  float4 v = ((const float4*)in)[i];
  bf16_4 r{(bf16_t)v.x, (bf16_t)v.y, (bf16_t)v.z, (bf16_t)v.w};
  ((bf16_4*)out)[i] = r;
}

// ------------- transpose + cast weight: W (K x N) fp32 -> Wt (Np x K) bf16 -------------
__global__ void transpose_cast(const float* __restrict__ W, bf16_t* __restrict__ Wt,
                               int K, int N, int Np) {
  __shared__ float tile[32][33];
  int k0 = blockIdx.x * 32, n0 = blockIdx.y * 32;
  int tx = threadIdx.x, ty = threadIdx.y;
#pragma unroll
  for (int i = 0; i < 4; ++i) {
    int k = k0 + ty + i * 8, n = n0 + tx;
    float v = (k < K && n < N) ? W[(size_t)k * N + n] : 0.f;
    tile[ty + i * 8][tx] = v;
  }
  __syncthreads();
#pragma unroll
  for (int i = 0; i < 4; ++i) {
    int n = n0 + ty + i * 8, k = k0 + tx;
    if (n < Np && k < K) Wt[(size_t)n * K + k] = (bf16_t)tile[tx][ty + i * 8];
  }
}

// ------------- transpose V: Vbuf[BT][2048] -> Vt[bh=32][128][T] -------------
__global__ void transpose_v(const bf16_t* __restrict__ V, bf16_t* __restrict__ Vt) {
  __shared__ bf16_t tile[64 * 64];
  int id = blockIdx.x;
  int t0 = (id & 31) * 64;
  int d0 = ((id >> 5) & 1) * 64;
  int bh = id >> 6;  // 0..31
  int b = bh >> 4, h = bh & 15;
  int t = threadIdx.x;
#pragma unroll
  for (int it = 0; it < 2; ++it) {
    int idx = it * 256 + t;
    int tt = idx >> 3, c = idx & 7;
    bf16x8 v = *(const bf16x8*)&V[(size_t)(b * T_ + t0 + tt) * 2048 + h * 128 + d0 + c * 8];
    int sw = (tt ^ (tt >> 3)) & 7;
    *(bf16x8*)((char*)tile + tt * 128 + 16 * (c ^ sw)) = v;
  }
  __syncthreads();
#pragma unroll
  for (int it = 0; it < 2; ++it) {
    int idx = it * 256 + t;
    int dr = idx >> 3, c = idx & 7;
    bf16_t tmp[8];
#pragma unroll
    for (int u = 0; u < 8; ++u) {
      int sw = (u ^ c) & 7;
      tmp[u] = *(const bf16_t*)((const char*)tile + (8 * c + u) * 128 + ((2 * dr) ^ (16 * sw)));
    }
    *(bf16x8*)&Vt[((size_t)bh * 128 + d0 + dr) * T_ + t0 + c * 8] = *(bf16x8*)tmp;
  }
}

// ---------------- GEMM: C = A(MxK) * Bt(NxK)^T, bf16 in, fp32 acc ----------------
// MODE 1: store fp32 to C0, row stride ldc
// MODE 3: col<512 -> C0 (q_c); col<1024 -> C1 (kv_c); col<1088 -> C2 (k_rb); else skip
// MODE 4: col<2048 -> C0 head-interleaved (Qbuf); else -> C1 ld 1024 (q_rb)
// MODE 5: col<2048 -> C0 head-interleaved (Kbuf); else -> C1 ld 2048 (Vbuf)
template <int MODE>
__global__ __launch_bounds__(256) void gemm_bt(const bf16_t* __restrict__ A,
                                               const bf16_t* __restrict__ Bt,
                                               void* __restrict__ C0v,
                                               void* __restrict__ C1v,
                                               void* __restrict__ C2v,
                                               int M, int N, int K, int ldc) {
  __shared__ bf16_t As[128 * 32];
  __shared__ bf16_t Bs[128 * 32];
  const int t = threadIdx.x;
  const int w = t >> 6, l = t & 63, l15 = l & 15, lhi = l >> 4;
  const int m0 = blockIdx.y * 128, n0 = blockIdx.x * 128;
  const int wr = (w >> 1) * 64, wc = (w & 1) * 64;

  f32x4 zero = {0.f, 0.f, 0.f, 0.f};
  f32x4 acc[4][4];
#pragma unroll
  for (int m = 0; m < 4; ++m)
#pragma unroll
    for (int n = 0; n < 4; ++n) acc[m][n] = zero;

  const int e0 = t * 8;
  const int r0 = e0 >> 5, c0 = e0 & 31;
  const int e1 = 2048 + t * 8;
  const int r1 = e1 >> 5, c1 = e1 & 31;

  for (int k0 = 0; k0 < K; k0 += 32) {
    gload16(A + (size_t)(m0 + r0) * K + k0 + c0, &As[e0]);
    gload16(A + (size_t)(m0 + r1) * K + k0 + c1, &As[e1]);
    gload16(Bt + (size_t)(n0 + r0) * K + k0 + c0, &Bs[e0]);
    gload16(Bt + (size_t)(n0 + r1) * K + k0 + c1, &Bs[e1]);
    __syncthreads();
    bf16x8 af[4], bfr[4];
#pragma unroll
    for (int m = 0; m < 4; ++m)
      af[m] = *(const bf16x8*)&As[(wr + m * 16 + l15) * 32 + lhi * 8];
#pragma unroll
    for (int n = 0; n < 4; ++n)
      bfr[n] = *(const bf16x8*)&Bs[(wc + n * 16 + l15) * 32 + lhi * 8];
#pragma unroll
    for (int m = 0; m < 4; ++m)
#pragma unroll
      for (int n = 0; n < 4; ++n)
        acc[m][n] = __builtin_amdgcn_mfma_f32_16x16x32_bf16(af[m], bfr[n], acc[m][n], 0, 0, 0);
    __syncthreads();
  }

#pragma unroll
  for (int m = 0; m < 4; ++m) {
#pragma unroll
    for (int n = 0; n < 4; ++n) {
#pragma unroll
      for (int r = 0; r < 4; ++r) {
        int row = m0 + wr + m * 16 + lhi * 4 + r;
        int col = n0 + wc + n * 16 + l15;
        float v = acc[m][n][r];
        if (MODE == 1) {
          ((float*)C0v)[(size_t)row * ldc + col] = v;
        } else if (MODE == 3) {
          if (col < 512)       ((bf16_t*)C0v)[(size_t)row * 512 + col] = (bf16_t)v;
          else if (col < 1024) ((bf16_t*)C1v)[(size_t)row * 512 + (col - 512)] = (bf16_t)v;
          else if (col < 1088) ((bf16_t*)C2v)[(size_t)row * 64 + (col - 1024)] = (bf16_t)v;
        } else if (MODE == 4) {
          if (col < 2048) ((bf16_t*)C0v)[(size_t)row * QSTRIDE_ + (col >> 7) * DQK_ + (col & 127)] = (bf16_t)v;
          else            ((bf16_t*)C1v)[(size_t)row * 1024 + (col - 2048)] = (bf16_t)v;
        } else if (MODE == 5) {
          if (col < 2048) ((bf16_t*)C0v)[(size_t)row * QSTRIDE_ + (col >> 7) * DQK_ + (col & 127)] = (bf16_t)v;
          else            ((bf16_t*)C1v)[(size_t)row * 2048 + (col - 2048)] = (bf16_t)v;
        }
      }
    }
  }
}

// ---------------- RoPE epilogues ----------------
__global__ void rope_q(const bf16_t* __restrict__ qr, const float* __restrict__ fr,
                       bf16_t* __restrict__ Q) {
  int idx = blockIdx.x * 256 + threadIdx.x;  // BT_*H_*32
  int j = idx & 31;
  int h = (idx >> 5) & 15;
  int row = idx >> 9;
  int tt = row & (T_ - 1);
  float x1 = (float)qr[(size_t)row * 1024 + h * 64 + 2 * j];
  float x2 = (float)qr[(size_t)row * 1024 + h * 64 + 2 * j + 1];
  float c = fr[tt * 64 + 2 * j], s = fr[tt * 64 + 2 * j + 1];
  bf16_t o0 = (bf16_t)(x1 * c - x2 * s);
  bf16_t o1 = (bf16_t)(x1 * s + x2 * c);
  size_t o = (size_t)row * QSTRIDE_ + h * DQK_ + 128 + 2 * j;
  Q[o] = o0;
  Q[o + 1] = o1;
}

__global__ void rope_k(const bf16_t* __restrict__ kr, const float* __restrict__ fr,
                       bf16_t* __restrict__ Kb) {
  int idx = blockIdx.x * 256 + threadIdx.x;  // BT_*32
  int j = idx & 31;
  int row = idx >> 5;
  int tt = row & (T_ - 1);
  float x1 = (float)kr[(size_t)row * 64 + 2 * j];
  float x2 = (float)kr[(size_t)row * 64 + 2 * j + 1];
  float c = fr[tt * 64 + 2 * j], s = fr[tt * 64 + 2 * j + 1];
  union { bf16_t h2[2]; unsigned u; } pk;
  pk.h2[0] = (bf16_t)(x1 * c - x2 * s);
  pk.h2[1] = (bf16_t)(x1 * s + x2 * c);
#pragma unroll
  for (int h = 0; h < H_; ++h) {
    *(unsigned*)&Kb[(size_t)row * QSTRIDE_ + h * DQK_ + 128 + 2 * j] = pk.u;
  }
}

// ---------------- causal flash attention v5 ----------------
// v3 shell (512 blocks x 256 threads, reg-staged single-buffered K/V, 2 barriers/kt,
// 2 blocks/CU) + v4 wave layout: waves {0,1} own 64-row subtile qa (rows 0-31 / 32-63),
// waves {2,3} own subtile qb = 31-qa. Each wave covers 32 q-rows with 2 fragment sets
// sharing every kf/vf LDS read -> LDS read traffic per q-row halved vs v3.
// Grid id mapping pairs blocks c and c+256 with complementary runtimes (sum 49 steps).
#define KLDB 200
#define VLDB 72
#define PLDB 68

__global__ __launch_bounds__(256, 2) void flash_attn5(const bf16_t* __restrict__ Q,
                                                      const bf16_t* __restrict__ Kb,
                                                      const bf16_t* __restrict__ Vt,
                                                      bf16_t* __restrict__ Ob) {
  __shared__ bf16_t Ks[64 * KLDB];     // 25600 B
  __shared__ bf16_t Vs[128 * VLDB];    // 18432 B
  __shared__ bf16_t Ps[4][32 * PLDB];  // 17408 B   (total 61440 -> 2 blocks/CU)

  const int t = threadIdx.x, w = t >> 6, l = t & 63, l15 = l & 15, lhi = l >> 4;
  const int id = blockIdx.x;
  int bh, qp;
  if (id < 256) { bh = id & 31; qp = id >> 5; }            // qp 0..7
  else          { int j = id - 256; bh = j & 31; qp = 15 - (j >> 5); }  // qp 15..8
  const int b = bh >> 4, h = bh & 15;
  const int qa = qp, qb = 31 - qp;                         // qa < qb
  const int q_s = (w >= 2) ? qb : qa;                      // wave's 64-row q-tile
  const int wrow = (w & 1) * 32;                           // row offset within subtile
  const float scale = 0.07216878364870322f;                // 1/sqrt(192)

  // staging thread->slot maps (identical to v3)
  int rK[6], cK[6];
#pragma unroll
  for (int i = 0; i < 6; ++i) { int idx = i * 256 + t; rK[i] = idx / 24; cK[i] = idx % 24; }
  const int rVt = t >> 3, cV = t & 7;
  const bf16_t* kbase = Kb + (size_t)b * T_ * QSTRIDE_ + h * DQK_;
  const bf16_t* vbase = Vt + (size_t)bh * DH_ * T_;

  bf16x8 kreg[6], vreg[4];
#define LOAD_TILE(K0)                                                                      \
  do {                                                                                     \
    _Pragma("unroll") for (int i = 0; i < 6; ++i)                                          \
        kreg[i] = *(const bf16x8*)(kbase + (size_t)((K0) + rK[i]) * QSTRIDE_ + cK[i] * 8); \
    _Pragma("unroll") for (int i = 0; i < 4; ++i)                                          \
        vreg[i] = *(const bf16x8*)(vbase + (size_t)(i * 32 + rVt) * T_ + (K0) + cV * 8);   \
  } while (0)
#define WRITE_TILE()                                                                       \
  do {                                                                                     \
    _Pragma("unroll") for (int i = 0; i < 6; ++i)                                          \
        *(bf16x8*)&Ks[rK[i] * KLDB + cK[i] * 8] = kreg[i];                                 \
    _Pragma("unroll") for (int i = 0; i < 4; ++i)                                          \
        *(bf16x8*)&Vs[(i * 32 + rVt) * VLDB + cV * 8] = vreg[i];                           \
  } while (0)

  f32x4 zero = {0.f, 0.f, 0.f, 0.f};

  // Q fragments: 32 rows per wave (2 sets of 16)
  bf16x8 qf[2][6];
#pragma unroll
  for (int u = 0; u < 2; ++u) {
    const bf16_t* qrow =
        Q + ((size_t)(b * T_ + q_s * 64 + wrow + u * 16 + l15)) * QSTRIDE_ + h * DQK_;
#pragma unroll
    for (int kc = 0; kc < 6; ++kc) qf[u][kc] = *(const bf16x8*)(qrow + kc * 32 + lhi * 8);
  }

  float m_r[2][4], l_r[2][4];
  f32x4 accO[2][8];
#pragma unroll
  for (int u = 0; u < 2; ++u) {
#pragma unroll
    for (int r = 0; r < 4; ++r) { m_r[u][r] = -1e30f; l_r[u][r] = 0.f; }
#pragma unroll
    for (int n = 0; n < 8; ++n) accO[u][n] = zero;
  }

  LOAD_TILE(0);
  WRITE_TILE();
  __syncthreads();

  for (int kt = 0; kt <= qb; ++kt) {
    if (kt < qb) LOAD_TILE((kt + 1) * 64);  // prefetch into regs (in flight during compute)

    if (kt <= q_s) {
      const bool diag = (kt == q_s);

      // QK^T: each kf read feeds both fragment sets
      f32x4 s[2][4];
#pragma unroll
      for (int u = 0; u < 2; ++u)
#pragma unroll
        for (int n = 0; n < 4; ++n) s[u][n] = zero;
      __builtin_amdgcn_s_setprio(1);
#pragma unroll
      for (int kc = 0; kc < 6; ++kc) {
#pragma unroll
        for (int n = 0; n < 4; ++n) {
          bf16x8 kf = *(const bf16x8*)&Ks[(n * 16 + l15) * KLDB + kc * 32 + lhi * 8];
          s[0][n] = __builtin_amdgcn_mfma_f32_16x16x32_bf16(qf[0][kc], kf, s[0][n], 0, 0, 0);
          s[1][n] = __builtin_amdgcn_mfma_f32_16x16x32_bf16(qf[1][kc], kf, s[1][n], 0, 0, 0);
        }
      }
      __builtin_amdgcn_s_setprio(0);

      // softmax per fragment set
#pragma unroll
      for (int u = 0; u < 2; ++u) {
#pragma unroll
        for (int n = 0; n < 4; ++n)
#pragma unroll
          for (int r = 0; r < 4; ++r) {
            float v = s[u][n][r] * scale;
            if (diag) {
              int qq = wrow + u * 16 + lhi * 4 + r;  // row within 64-row tile
              int kk = n * 16 + l15;
              if (kk > qq) v = -1e30f;
            }
            s[u][n][r] = v;
          }
        float mn[4], corr[4];
#pragma unroll
        for (int r = 0; r < 4; ++r) {
          float v = fmaxf(fmaxf(s[u][0][r], s[u][1][r]), fmaxf(s[u][2][r], s[u][3][r]));
#pragma unroll
          for (int off = 1; off < 16; off <<= 1) v = fmaxf(v, __shfl_xor(v, off, 64));
          mn[r] = fmaxf(m_r[u][r], v);
          corr[r] = __expf(m_r[u][r] - mn[r]);
          m_r[u][r] = mn[r];
        }
        float rs[4] = {0.f, 0.f, 0.f, 0.f};
#pragma unroll
        for (int n = 0; n < 4; ++n)
#pragma unroll
          for (int r = 0; r < 4; ++r) {
            float p = __expf(s[u][n][r] - mn[r]);
            rs[r] += p;
            Ps[w][(u * 16 + lhi * 4 + r) * PLDB + n * 16 + l15] = (bf16_t)p;
          }
#pragma unroll
        for (int r = 0; r < 4; ++r) {
          float v = rs[r];
#pragma unroll
          for (int off = 1; off < 16; off <<= 1) v += __shfl_xor(v, off, 64);
          l_r[u][r] = l_r[u][r] * corr[r] + v;
        }
#pragma unroll
        for (int n = 0; n < 8; ++n)
#pragma unroll
          for (int r = 0; r < 4; ++r) accO[u][n][r] *= corr[r];
      }

      // PV: each vf read feeds both fragment sets
      __builtin_amdgcn_s_setprio(1);
#pragma unroll
      for (int kc = 0; kc < 2; ++kc) {
        bf16x8 pf[2];
#pragma unroll
        for (int u = 0; u < 2; ++u) {
          const bf16_t* pb = &Ps[w][(u * 16 + l15) * PLDB + kc * 32 + lhi * 8];
          bf16x4 p0 = *(const bf16x4*)pb;
          bf16x4 p1 = *(const bf16x4*)(pb + 4);
          pf[u] = __builtin_shufflevector(p0, p1, 0, 1, 2, 3, 4, 5, 6, 7);
        }
#pragma unroll
        for (int n = 0; n < 8; ++n) {
          bf16x8 vf = *(const bf16x8*)&Vs[(n * 16 + l15) * VLDB + kc * 32 + lhi * 8];
          accO[0][n] = __builtin_amdgcn_mfma_f32_16x16x32_bf16(pf[0], vf, accO[0][n], 0, 0, 0);
          accO[1][n] = __builtin_amdgcn_mfma_f32_16x16x32_bf16(pf[1], vf, accO[1][n], 0, 0, 0);
        }
      }
      __builtin_amdgcn_s_setprio(0);
    }

    __syncthreads();            // all LDS reads of tile kt done
    if (kt < qb) WRITE_TILE();  // publish next tile
    __syncthreads();
  }

  // store O: 32 rows per wave
#pragma unroll
  for (int u = 0; u < 2; ++u) {
    float inv[4];
#pragma unroll
    for (int r = 0; r < 4; ++r) inv[r] = 1.0f / l_r[u][r];
#pragma unroll
    for (int n = 0; n < 8; ++n)
#pragma unroll
      for (int r = 0; r < 4; ++r) {
        size_t row = (size_t)(b * T_ + q_s * 64 + wrow + u * 16 + lhi * 4 + r);
        Ob[row * (H_ * DH_) + h * DH_ + n * 16 + l15] = (bf16_t)(accO[u][n][r] * inv[r]);
      }
  }
#undef LOAD_TILE
#undef WRITE_TILE
}

// ---------------- host ----------------
extern "C" void kernel_launch(void* const* d_in, const int* in_sizes, int n_in,
                              void* d_out, int out_size, void* d_ws, size_t ws_size,
                              hipStream_t stream) {
  (void)in_sizes; (void)n_in; (void)out_size; (void)ws_size;
  const float* x    = (const float*)d_in[0];
  const float* fr   = (const float*)d_in[1];
  // d_in[2] = mask (unused; causal handled analytically)
  const float* Wdq  = (const float*)d_in[3];
  const float* Wuq  = (const float*)d_in[4];
  const float* Wdkv = (const float*)d_in[5];
  const float* Wuk  = (const float*)d_in[6];
  const float* Wuv  = (const float*)d_in[7];
  const float* Wqr  = (const float*)d_in[8];
  const float* Wkr  = (const float*)d_in[9];
  const float* Wo   = (const float*)d_in[10];
  float* out = (float*)d_out;

  char* ws = (char*)d_ws;
  size_t off = 0;
  auto alloc = [&](size_t bytes) -> void* {
    void* p = ws + off;
    off += (bytes + 255) & ~(size_t)255;
    return p;
  };
  bf16_t* x_bf   = (bf16_t*)alloc((size_t)BT_ * DIM_ * 2);
  bf16_t* Bt1    = (bf16_t*)alloc((size_t)1152 * 2048 * 2);  // [Wdq(512) | Wdkv(512) | Wkr(128 pad)]
  bf16_t* Bt2    = (bf16_t*)alloc((size_t)3072 * 512 * 2);   // [Wuq(2048) | Wqr(1024)]
  bf16_t* Bt3    = (bf16_t*)alloc((size_t)4096 * 512 * 2);   // [Wuk(2048) | Wuv(2048)]
  bf16_t* Wo_t   = (bf16_t*)alloc((size_t)2048 * 2048 * 2);
  bf16_t* q_c    = (bf16_t*)alloc((size_t)BT_ * 512 * 2);
  bf16_t* kv_c   = (bf16_t*)alloc((size_t)BT_ * 512 * 2);
  bf16_t* q_rb   = (bf16_t*)alloc((size_t)BT_ * 1024 * 2);
  bf16_t* k_rb   = (bf16_t*)alloc((size_t)BT_ * 64 * 2);
  bf16_t* Qbuf   = (bf16_t*)alloc((size_t)BT_ * QSTRIDE_ * 2);
  bf16_t* Kbuf   = (bf16_t*)alloc((size_t)BT_ * QSTRIDE_ * 2);
  bf16_t* Vbuf   = (bf16_t*)alloc((size_t)BT_ * 2048 * 2);
  bf16_t* Vt_g   = (bf16_t*)alloc((size_t)BT_ * 2048 * 2);
  bf16_t* AObuf  = (bf16_t*)alloc((size_t)BT_ * 2048 * 2);

  dim3 tb(32, 8);
  cast_f32_bf16<<<(BT_ * DIM_ / 4 + 255) / 256, 256, 0, stream>>>(x, x_bf, BT_ * DIM_ / 4);
  transpose_cast<<<dim3(64, 16), tb, 0, stream>>>(Wdq,  Bt1,                        2048, 512, 512);
  transpose_cast<<<dim3(64, 16), tb, 0, stream>>>(Wdkv, Bt1 + (size_t)512 * 2048,   2048, 512, 512);
  transpose_cast<<<dim3(64, 4),  tb, 0, stream>>>(Wkr,  Bt1 + (size_t)1024 * 2048,  2048, 64, 128);
  transpose_cast<<<dim3(16, 64), tb, 0, stream>>>(Wuq,  Bt2,                        512, 2048, 2048);
  transpose_cast<<<dim3(16, 32), tb, 0, stream>>>(Wqr,  Bt2 + (size_t)2048 * 512,   512, 1024, 1024);
  transpose_cast<<<dim3(16, 64), tb, 0, stream>>>(Wuk,  Bt3,                        512, 2048, 2048);
  transpose_cast<<<dim3(16, 64), tb, 0, stream>>>(Wuv,  Bt3 + (size_t)2048 * 512,   512, 2048, 2048);
  transpose_cast<<<dim3(64, 64), tb, 0, stream>>>(Wo,   Wo_t,                       2048, 2048, 2048);

  // fused projections
  gemm_bt<3><<<dim3(9, 32),  256, 0, stream>>>(x_bf, Bt1, q_c, kv_c, k_rb, BT_, 1088, 2048, 0);
  gemm_bt<4><<<dim3(24, 32), 256, 0, stream>>>(q_c,  Bt2, Qbuf, q_rb, nullptr, BT_, 3072, 512, 0);
  gemm_bt<5><<<dim3(32, 32), 256, 0, stream>>>(kv_c, Bt3, Kbuf, Vbuf, nullptr, BT_, 4096, 512, 0);

  transpose_v<<<2048, 256, 0, stream>>>(Vbuf, Vt_g);

  rope_q<<<(BT_ * H_ * 32) / 256, 256, 0, stream>>>(q_rb, fr, Qbuf);
  rope_k<<<(BT_ * 32) / 256, 256, 0, stream>>>(k_rb, fr, Kbuf);

  flash_attn5<<<512, 256, 0, stream>>>(Qbuf, Kbuf, Vt_g, AObuf);

  // output projection -> fp32
  gemm_bt<1><<<dim3(16, 32), 256, 0, stream>>>(AObuf, Wo_t, out, nullptr, nullptr, BT_, 2048, 2048, 2048);
}

// Round 8
// 318.740 us; speedup vs baseline: 1.1889x; 1.0888x over previous
//
#include <hip/hip_runtime.h>
#include <hip/hip_bf16.h>
#include <cstdint>
#include <cstddef>

typedef __bf16 bf16_t;
typedef __attribute__((ext_vector_type(8))) __bf16 bf16x8;
typedef __attribute__((ext_vector_type(4))) __bf16 bf16x4;
typedef __attribute__((ext_vector_type(4))) float f32x4;

#define B_ 2
#define T_ 2048
#define DIM_ 2048
#define H_ 16
#define DH_ 128
#define DD_ 64
#define DQK_ 192              // DH_ + DD_
#define QSTRIDE_ 3072         // H_ * DQK_
#define BT_ 4096              // B_ * T_

__device__ __forceinline__ void gload16(const void* g, void* lds) {
  __builtin_amdgcn_global_load_lds(
      (const __attribute__((address_space(1))) unsigned int*)g,
      (__attribute__((address_space(3))) unsigned int*)lds, 16, 0, 0);
}

// ---------------- cast x (fp32 -> bf16, vectorized) ----------------
struct bf16_4 { bf16_t a, b, c, d; };
__global__ void cast_f32_bf16(const float* __restrict__ in, bf16_t* __restrict__ out, int n4) {
  int i = blockIdx.x * blockDim.x + threadIdx.x;
  if (i >= n4) return;
  float4 v = ((const float4*)in)[i];
  bf16_4 r{(bf16_t)v.x, (bf16_t)v.y, (bf16_t)v.z, (bf16_t)v.w};
  ((bf16_4*)out)[i] = r;
}

// ------------- ALL weight transposes in ONE launch -------------
// W (K x N) fp32 -> Wt (Np x K) bf16, zero-fill rows n >= N.
__global__ void transpose_all(const float* __restrict__ Wdq, const float* __restrict__ Wdkv,
                              const float* __restrict__ Wkr, const float* __restrict__ Wuq,
                              const float* __restrict__ Wqr, const float* __restrict__ Wuk,
                              const float* __restrict__ Wuv, const float* __restrict__ Wo,
                              bf16_t* __restrict__ Bt1, bf16_t* __restrict__ Bt2,
                              bf16_t* __restrict__ Bt3, bf16_t* __restrict__ Wo_t) {
  __shared__ float tile[32][33];
  int id = blockIdx.x;
  const float* W; bf16_t* Wt; int K, N, Np, kt;
  if (id < 1024)      { W = Wdq;  Wt = Bt1;                          K = 2048; N = 512;  Np = 512;  kt = 64; }
  else if (id < 2048) { W = Wdkv; Wt = Bt1 + (size_t)512 * 2048;  id -= 1024; K = 2048; N = 512;  Np = 512;  kt = 64; }
  else if (id < 2304) { W = Wkr;  Wt = Bt1 + (size_t)1024 * 2048; id -= 2048; K = 2048; N = 64;   Np = 128;  kt = 64; }
  else if (id < 3328) { W = Wuq;  Wt = Bt2;                       id -= 2304; K = 512;  N = 2048; Np = 2048; kt = 16; }
  else if (id < 3840) { W = Wqr;  Wt = Bt2 + (size_t)2048 * 512;  id -= 3328; K = 512;  N = 1024; Np = 1024; kt = 16; }
  else if (id < 4864) { W = Wuk;  Wt = Bt3;                       id -= 3840; K = 512;  N = 2048; Np = 2048; kt = 16; }
  else if (id < 5888) { W = Wuv;  Wt = Bt3 + (size_t)2048 * 512;  id -= 4864; K = 512;  N = 2048; Np = 2048; kt = 16; }
  else                { W = Wo;   Wt = Wo_t;                      id -= 5888; K = 2048; N = 2048; Np = 2048; kt = 64; }
  int k0 = (id % kt) * 32, n0 = (id / kt) * 32;
  int tx = threadIdx.x, ty = threadIdx.y;
#pragma unroll
  for (int i = 0; i < 4; ++i) {
    int k = k0 + ty + i * 8, n = n0 + tx;
    float v = (k < K && n < N) ? W[(size_t)k * N + n] : 0.f;
    tile[ty + i * 8][tx] = v;
  }
  __syncthreads();
#pragma unroll
  for (int i = 0; i < 4; ++i) {
    int n = n0 + ty + i * 8, k = k0 + tx;
    if (n < Np && k < K) Wt[(size_t)n * K + k] = (bf16_t)tile[tx][ty + i * 8];
  }
}

// ------------- transpose V: Vbuf[BT][2048] -> Vt[bh=32][128][T] -------------
__global__ void transpose_v(const bf16_t* __restrict__ V, bf16_t* __restrict__ Vt) {
  __shared__ bf16_t tile[64 * 64];
  int id = blockIdx.x;
  int t0 = (id & 31) * 64;
  int d0 = ((id >> 5) & 1) * 64;
  int bh = id >> 6;  // 0..31
  int b = bh >> 4, h = bh & 15;
  int t = threadIdx.x;
#pragma unroll
  for (int it = 0; it < 2; ++it) {
    int idx = it * 256 + t;
    int tt = idx >> 3, c = idx & 7;
    bf16x8 v = *(const bf16x8*)&V[(size_t)(b * T_ + t0 + tt) * 2048 + h * 128 + d0 + c * 8];
    int sw = (tt ^ (tt >> 3)) & 7;
    *(bf16x8*)((char*)tile + tt * 128 + 16 * (c ^ sw)) = v;
  }
  __syncthreads();
#pragma unroll
  for (int it = 0; it < 2; ++it) {
    int idx = it * 256 + t;
    int dr = idx >> 3, c = idx & 7;
    bf16_t tmp[8];
#pragma unroll
    for (int u = 0; u < 8; ++u) {
      int sw = (u ^ c) & 7;
      tmp[u] = *(const bf16_t*)((const char*)tile + (8 * c + u) * 128 + ((2 * dr) ^ (16 * sw)));
    }
    *(bf16x8*)&Vt[((size_t)bh * 128 + d0 + dr) * T_ + t0 + c * 8] = *(bf16x8*)tmp;
  }
}

// ---------------- GEMM: C = A(MxK) * Bt(NxK)^T, bf16 in, fp32 acc ----------------
// MODE 1: store fp32 to C0, row stride ldc
// MODE 3: col<512 -> C0 (q_c); col<1024 -> C1 (kv_c); col<1088 -> C2 (k_rb); else skip
// MODE 4: col<2048 -> C0 head-interleaved (Qbuf); else -> in-register RoPE -> Qbuf[...+128+idx]
// MODE 5: col<2048 -> C0 head-interleaved (Kbuf); else -> C1 ld 2048 (Vbuf)
template <int MODE>
__global__ __launch_bounds__(256) void gemm_bt(const bf16_t* __restrict__ A,
                                               const bf16_t* __restrict__ Bt,
                                               void* __restrict__ C0v,
                                               void* __restrict__ C1v,
                                               void* __restrict__ C2v,
                                               const float* __restrict__ fr,
                                               int M, int N, int K, int ldc) {
  __shared__ bf16_t As[128 * 32];
  __shared__ bf16_t Bs[128 * 32];
  const int t = threadIdx.x;
  const int w = t >> 6, l = t & 63, l15 = l & 15, lhi = l >> 4;
  const int m0 = blockIdx.y * 128, n0 = blockIdx.x * 128;
  const int wr = (w >> 1) * 64, wc = (w & 1) * 64;

  f32x4 zero = {0.f, 0.f, 0.f, 0.f};
  f32x4 acc[4][4];
#pragma unroll
  for (int m = 0; m < 4; ++m)
#pragma unroll
    for (int n = 0; n < 4; ++n) acc[m][n] = zero;

  const int e0 = t * 8;
  const int r0 = e0 >> 5, c0 = e0 & 31;
  const int e1 = 2048 + t * 8;
  const int r1 = e1 >> 5, c1 = e1 & 31;

  for (int k0 = 0; k0 < K; k0 += 32) {
    gload16(A + (size_t)(m0 + r0) * K + k0 + c0, &As[e0]);
    gload16(A + (size_t)(m0 + r1) * K + k0 + c1, &As[e1]);
    gload16(Bt + (size_t)(n0 + r0) * K + k0 + c0, &Bs[e0]);
    gload16(Bt + (size_t)(n0 + r1) * K + k0 + c1, &Bs[e1]);
    __syncthreads();
    bf16x8 af[4], bfr[4];
#pragma unroll
    for (int m = 0; m < 4; ++m)
      af[m] = *(const bf16x8*)&As[(wr + m * 16 + l15) * 32 + lhi * 8];
#pragma unroll
    for (int n = 0; n < 4; ++n)
      bfr[n] = *(const bf16x8*)&Bs[(wc + n * 16 + l15) * 32 + lhi * 8];
#pragma unroll
    for (int m = 0; m < 4; ++m)
#pragma unroll
      for (int n = 0; n < 4; ++n)
        acc[m][n] = __builtin_amdgcn_mfma_f32_16x16x32_bf16(af[m], bfr[n], acc[m][n], 0, 0, 0);
    __syncthreads();
  }

#pragma unroll
  for (int m = 0; m < 4; ++m) {
#pragma unroll
    for (int n = 0; n < 4; ++n) {
#pragma unroll
      for (int r = 0; r < 4; ++r) {
        int row = m0 + wr + m * 16 + lhi * 4 + r;
        int col = n0 + wc + n * 16 + l15;
        float v = acc[m][n][r];
        if (MODE == 1) {
          ((float*)C0v)[(size_t)row * ldc + col] = v;
        } else if (MODE == 3) {
          if (col < 512)       ((bf16_t*)C0v)[(size_t)row * 512 + col] = (bf16_t)v;
          else if (col < 1024) ((bf16_t*)C1v)[(size_t)row * 512 + (col - 512)] = (bf16_t)v;
          else if (col < 1088) ((bf16_t*)C2v)[(size_t)row * 64 + (col - 1024)] = (bf16_t)v;
        } else if (MODE == 4) {
          if (col < 2048) {
            ((bf16_t*)C0v)[(size_t)row * QSTRIDE_ + (col >> 7) * DQK_ + (col & 127)] = (bf16_t)v;
          } else {
            // fused RoPE: pair (2j,2j+1) lives in adjacent lanes (l15 parity)
            float other = __shfl_xor(v, 1, 64);
            int tt = row & (T_ - 1);
            int j = (col & 63) >> 1;
            float2 cs = ((const float2*)fr)[tt * 32 + j];
            float o = (col & 1) ? (other * cs.y + v * cs.x) : (v * cs.x - other * cs.y);
            int hh = (col - 2048) >> 6;
            ((bf16_t*)C0v)[(size_t)row * QSTRIDE_ + hh * DQK_ + 128 + (col & 63)] = (bf16_t)o;
          }
        } else if (MODE == 5) {
          if (col < 2048) ((bf16_t*)C0v)[(size_t)row * QSTRIDE_ + (col >> 7) * DQK_ + (col & 127)] = (bf16_t)v;
          else            ((bf16_t*)C1v)[(size_t)row * 2048 + (col - 2048)] = (bf16_t)v;
        }
      }
    }
  }
}

// ---------------- RoPE-k epilogue (rotate + broadcast to 16 heads) ----------------
__global__ void rope_k(const bf16_t* __restrict__ kr, const float* __restrict__ fr,
                       bf16_t* __restrict__ Kb) {
  int idx = blockIdx.x * 256 + threadIdx.x;  // BT_*32
  int j = idx & 31;
  int row = idx >> 5;
  int tt = row & (T_ - 1);
  float x1 = (float)kr[(size_t)row * 64 + 2 * j];
  float x2 = (float)kr[(size_t)row * 64 + 2 * j + 1];
  float c = fr[tt * 64 + 2 * j], s = fr[tt * 64 + 2 * j + 1];
  union { bf16_t h2[2]; unsigned u; } pk;
  pk.h2[0] = (bf16_t)(x1 * c - x2 * s);
  pk.h2[1] = (bf16_t)(x1 * s + x2 * c);
#pragma unroll
  for (int h = 0; h < H_; ++h) {
    *(unsigned*)&Kb[(size_t)row * QSTRIDE_ + h * DQK_ + 128 + 2 * j] = pk.u;
  }
}

// ---------------- causal flash attention v3 (proven 118 us) ----------------
// 512 blocks x 256 threads. Block handles q-tile pair {qp, 31-qp} SEQUENTIALLY
// (33 tile-steps, balanced, single live register set -> no spills).
#define KLDB 200
#define VLDB 72
#define PLDB 68

__global__ __launch_bounds__(256, 2) void flash_attn3(const bf16_t* __restrict__ Q,
                                                      const bf16_t* __restrict__ Kb,
                                                      const bf16_t* __restrict__ Vt,
                                                      bf16_t* __restrict__ Ob) {
  __shared__ bf16_t Ks[64 * KLDB];
  __shared__ bf16_t Vs[128 * VLDB];
  __shared__ bf16_t Ps[4][16 * PLDB];

  const int t = threadIdx.x, w = t >> 6, l = t & 63, l15 = l & 15, lhi = l >> 4;
  const int id = blockIdx.x;
  const int xcd = id & 7, sub = id >> 3;
  const int bh = xcd * 4 + (sub >> 4);
  const int qp = sub & 15;
  const int b = bh >> 4, h = bh & 15;
  const int qa = qp, qb = 31 - qp;  // qa < qb always
  const float scale = 0.07216878364870322f;  // 1/sqrt(192)

  // staging thread->slot maps
  int rK[6], cK[6];
#pragma unroll
  for (int i = 0; i < 6; ++i) { int idx = i * 256 + t; rK[i] = idx / 24; cK[i] = idx % 24; }
  const int rVt = t >> 3, cV = t & 7;
  const bf16_t* kbase = Kb + (size_t)b * T_ * QSTRIDE_ + h * DQK_;
  const bf16_t* vbase = Vt + (size_t)bh * DH_ * T_;

  bf16x8 kreg[6], vreg[4];
#define LOAD_TILE(K0)                                                                      \
  do {                                                                                     \
    _Pragma("unroll") for (int i = 0; i < 6; ++i)                                          \
        kreg[i] = *(const bf16x8*)(kbase + (size_t)((K0) + rK[i]) * QSTRIDE_ + cK[i] * 8); \
    _Pragma("unroll") for (int i = 0; i < 4; ++i)                                          \
        vreg[i] = *(const bf16x8*)(vbase + (size_t)(i * 32 + rVt) * T_ + (K0) + cV * 8);   \
  } while (0)
#define WRITE_TILE()                                                                       \
  do {                                                                                     \
    _Pragma("unroll") for (int i = 0; i < 6; ++i)                                          \
        *(bf16x8*)&Ks[rK[i] * KLDB + cK[i] * 8] = kreg[i];                                 \
    _Pragma("unroll") for (int i = 0; i < 4; ++i)                                          \
        *(bf16x8*)&Vs[(i * 32 + rVt) * VLDB + cV * 8] = vreg[i];                           \
  } while (0)

  f32x4 zero = {0.f, 0.f, 0.f, 0.f};

  LOAD_TILE(0);
  WRITE_TILE();
  __syncthreads();

  for (int pass = 0; pass < 2; ++pass) {
    const int qt = pass ? qb : qa;

    bf16x8 qf[6];
    {
      const bf16_t* qrow = Q + ((size_t)(b * T_ + qt * 64 + w * 16 + l15)) * QSTRIDE_ + h * DQK_;
#pragma unroll
      for (int kc = 0; kc < 6; ++kc) qf[kc] = *(const bf16x8*)(qrow + kc * 32 + lhi * 8);
    }

    float m_r[4], l_r[4];
    f32x4 accO[8];
#pragma unroll
    for (int r = 0; r < 4; ++r) { m_r[r] = -1e30f; l_r[r] = 0.f; }
#pragma unroll
    for (int n = 0; n < 8; ++n) accO[n] = zero;

    for (int kt = 0; kt <= qt; ++kt) {
      const bool last = (kt == qt);
      const bool haveNext = !(pass == 1 && last);
      if (haveNext) LOAD_TILE(last ? 0 : (kt + 1) * 64);  // prefetch (tile 0 for next pass)

      f32x4 s[4];
#pragma unroll
      for (int n = 0; n < 4; ++n) s[n] = zero;
      __builtin_amdgcn_s_setprio(1);
#pragma unroll
      for (int kc = 0; kc < 6; ++kc) {
#pragma unroll
        for (int n = 0; n < 4; ++n) {
          bf16x8 kf = *(const bf16x8*)&Ks[(n * 16 + l15) * KLDB + kc * 32 + lhi * 8];
          s[n] = __builtin_amdgcn_mfma_f32_16x16x32_bf16(qf[kc], kf, s[n], 0, 0, 0);
        }
      }
      __builtin_amdgcn_s_setprio(0);

#pragma unroll
      for (int n = 0; n < 4; ++n)
#pragma unroll
        for (int r = 0; r < 4; ++r) {
          float v = s[n][r] * scale;
          if (last) {
            int qq = w * 16 + lhi * 4 + r;
            int kk = n * 16 + l15;
            if (kk > qq) v = -1e30f;
          }
          s[n][r] = v;
        }
      float mn[4], corr[4];
#pragma unroll
      for (int r = 0; r < 4; ++r) {
        float v = fmaxf(fmaxf(s[0][r], s[1][r]), fmaxf(s[2][r], s[3][r]));
#pragma unroll
        for (int off = 1; off < 16; off <<= 1) v = fmaxf(v, __shfl_xor(v, off, 64));
        mn[r] = fmaxf(m_r[r], v);
        corr[r] = __expf(m_r[r] - mn[r]);
        m_r[r] = mn[r];
      }
      float rs[4] = {0.f, 0.f, 0.f, 0.f};
#pragma unroll
      for (int n = 0; n < 4; ++n)
#pragma unroll
        for (int r = 0; r < 4; ++r) {
          float p = __expf(s[n][r] - mn[r]);
          rs[r] += p;
          Ps[w][(lhi * 4 + r) * PLDB + n * 16 + l15] = (bf16_t)p;
        }
#pragma unroll
      for (int r = 0; r < 4; ++r) {
        float v = rs[r];
#pragma unroll
        for (int off = 1; off < 16; off <<= 1) v += __shfl_xor(v, off, 64);
        l_r[r] = l_r[r] * corr[r] + v;
      }
#pragma unroll
      for (int n = 0; n < 8; ++n)
#pragma unroll
        for (int r = 0; r < 4; ++r) accO[n][r] *= corr[r];

      __builtin_amdgcn_s_setprio(1);
#pragma unroll
      for (int kc = 0; kc < 2; ++kc) {
        bf16x4 p0 = *(const bf16x4*)&Ps[w][l15 * PLDB + kc * 32 + lhi * 8];
        bf16x4 p1 = *(const bf16x4*)&Ps[w][l15 * PLDB + kc * 32 + lhi * 8 + 4];
        bf16x8 pf = __builtin_shufflevector(p0, p1, 0, 1, 2, 3, 4, 5, 6, 7);
#pragma unroll
        for (int n = 0; n < 8; ++n) {
          bf16x8 vf = *(const bf16x8*)&Vs[(n * 16 + l15) * VLDB + kc * 32 + lhi * 8];
          accO[n] = __builtin_amdgcn_mfma_f32_16x16x32_bf16(pf, vf, accO[n], 0, 0, 0);
        }
      }
      __builtin_amdgcn_s_setprio(0);

      __syncthreads();
      if (haveNext) WRITE_TILE();
      __syncthreads();
    }

    {
      float inv[4];
#pragma unroll
      for (int r = 0; r < 4; ++r) inv[r] = 1.0f / l_r[r];
#pragma unroll
      for (int n = 0; n < 8; ++n)
#pragma unroll
        for (int r = 0; r < 4; ++r) {
          size_t row = (size_t)(b * T_ + qt * 64 + w * 16 + lhi * 4 + r);
          Ob[row * (H_ * DH_) + h * DH_ + n * 16 + l15] = (bf16_t)(accO[n][r] * inv[r]);
        }
    }
  }
#undef LOAD_TILE
#undef WRITE_TILE
}

// ---------------- host ----------------
extern "C" void kernel_launch(void* const* d_in, const int* in_sizes, int n_in,
                              void* d_out, int out_size, void* d_ws, size_t ws_size,
                              hipStream_t stream) {
  (void)in_sizes; (void)n_in; (void)out_size; (void)ws_size;
  const float* x    = (const float*)d_in[0];
  const float* fr   = (const float*)d_in[1];
  // d_in[2] = mask (unused; causal handled analytically)
  const float* Wdq  = (const float*)d_in[3];
  const float* Wuq  = (const float*)d_in[4];
  const float* Wdkv = (const float*)d_in[5];
  const float* Wuk  = (const float*)d_in[6];
  const float* Wuv  = (const float*)d_in[7];
  const float* Wqr  = (const float*)d_in[8];
  const float* Wkr  = (const float*)d_in[9];
  const float* Wo   = (const float*)d_in[10];
  float* out = (float*)d_out;

  char* ws = (char*)d_ws;
  size_t off = 0;
  auto alloc = [&](size_t bytes) -> void* {
    void* p = ws + off;
    off += (bytes + 255) & ~(size_t)255;
    return p;
  };
  bf16_t* x_bf   = (bf16_t*)alloc((size_t)BT_ * DIM_ * 2);
  bf16_t* Bt1    = (bf16_t*)alloc((size_t)1152 * 2048 * 2);  // [Wdq(512) | Wdkv(512) | Wkr(128 pad)]
  bf16_t* Bt2    = (bf16_t*)alloc((size_t)3072 * 512 * 2);   // [Wuq(2048) | Wqr(1024)]
  bf16_t* Bt3    = (bf16_t*)alloc((size_t)4096 * 512 * 2);   // [Wuk(2048) | Wuv(2048)]
  bf16_t* Wo_t   = (bf16_t*)alloc((size_t)2048 * 2048 * 2);
  bf16_t* q_c    = (bf16_t*)alloc((size_t)BT_ * 512 * 2);
  bf16_t* kv_c   = (bf16_t*)alloc((size_t)BT_ * 512 * 2);
  bf16_t* k_rb   = (bf16_t*)alloc((size_t)BT_ * 64 * 2);
  bf16_t* Qbuf   = (bf16_t*)alloc((size_t)BT_ * QSTRIDE_ * 2);
  bf16_t* Kbuf   = (bf16_t*)alloc((size_t)BT_ * QSTRIDE_ * 2);
  bf16_t* Vbuf   = (bf16_t*)alloc((size_t)BT_ * 2048 * 2);
  bf16_t* Vt_g   = (bf16_t*)alloc((size_t)BT_ * 2048 * 2);
  bf16_t* AObuf  = (bf16_t*)alloc((size_t)BT_ * 2048 * 2);

  cast_f32_bf16<<<(BT_ * DIM_ / 4 + 255) / 256, 256, 0, stream>>>(x, x_bf, BT_ * DIM_ / 4);
  transpose_all<<<9984, dim3(32, 8), 0, stream>>>(Wdq, Wdkv, Wkr, Wuq, Wqr, Wuk, Wuv, Wo,
                                                  Bt1, Bt2, Bt3, Wo_t);

  // fused projections (MODE4 fuses RoPE-q into epilogue)
  gemm_bt<3><<<dim3(9, 32),  256, 0, stream>>>(x_bf, Bt1, q_c, kv_c, k_rb, nullptr, BT_, 1088, 2048, 0);
  gemm_bt<4><<<dim3(24, 32), 256, 0, stream>>>(q_c,  Bt2, Qbuf, nullptr, nullptr, fr, BT_, 3072, 512, 0);
  gemm_bt<5><<<dim3(32, 32), 256, 0, stream>>>(kv_c, Bt3, Kbuf, Vbuf, nullptr, nullptr, BT_, 4096, 512, 0);

  transpose_v<<<2048, 256, 0, stream>>>(Vbuf, Vt_g);
  rope_k<<<(BT_ * 32) / 256, 256, 0, stream>>>(k_rb, fr, Kbuf);

  flash_attn3<<<512, 256, 0, stream>>>(Qbuf, Kbuf, Vt_g, AObuf);

  // output projection -> fp32
  gemm_bt<1><<<dim3(16, 32), 256, 0, stream>>>(AObuf, Wo_t, out, nullptr, nullptr, nullptr, BT_, 2048, 2048, 2048);
}